// Round 8
// baseline (154.487 us; speedup 1.0000x reference)
//
#include <hip/hip_runtime.h>
#include <cstddef>

typedef _Float16 f16_t;
typedef _Float16 f16x8 __attribute__((ext_vector_type(8)));
typedef float    f32x4  __attribute__((ext_vector_type(4)));
typedef float    f32x16 __attribute__((ext_vector_type(16)));

static constexpr int NN = 64;    // nodes
static constexpr int FF = 4;     // features
static constexpr int HH = 256;   // hidden

// ---- workspace layout (bytes) ----
// W2p    @ 0        : 131072   (W_msg2 packed 32x32x16 B-frags, f16)
// W1op   @ 131072   : 147456   (W_out1 padded/remapped 16x16x32, f16)
// W2op   @ 278528   : 131072   (W_out2 packed 16x16x32, f16)
// innode @ 409600   : 4718592  ([agg(256) | x(4) | pad(28)] f16, 8192 rows)
// Vp     @ 5128192  : 4194304  (V = x @ W1[4:8], f16 [128][64][256])
// Up     @ 9322496  : 4194304  (U = x @ W1[0:4] + b1, f16 [128][64][256])

// ------------------------------------------------------------------
// 16x16x32 B-frag pack: lane holds B[k=ks*32+(lane>>4)*8+j][col=nt*16+(lane&15)]
// ------------------------------------------------------------------
__device__ inline void pack_frag16(const float* __restrict__ src, f16_t* __restrict__ dst,
                                   int fid, int ksteps, int mode)
{
    if (fid >= ksteps * 1024) return;
    int lane = fid & 63;
    int nt   = (fid >> 6) & 15;
    int ks   = fid >> 10;
    int col  = nt * 16 + (lane & 15);
    int kb   = ks * 32 + (lane >> 4) * 8;
    #pragma unroll
    for (int j = 0; j < 8; ++j) {
        int k = kb + j;
        float v;
        if (mode == 0) {
            v = src[k * 256 + col];
        } else {
            if (k < 256)      v = src[(4 + k) * 256 + col];
            else if (k < 260) v = src[(k - 256) * 256 + col];
            else              v = 0.f;
        }
        dst[(size_t)fid * 8 + j] = (f16_t)v;
    }
}

// ------------------------------------------------------------------
// 32x32x16 B-frag pack: lane holds B[k=ks*16+(lane>>5)*8+j][col=nt*32+(lane&31)]
// ------------------------------------------------------------------
__device__ inline void pack_frag32(const float* __restrict__ src, f16_t* __restrict__ dst,
                                   int fid)
{
    int lane = fid & 63;
    int nt   = (fid >> 6) & 7;
    int ks   = fid >> 9;
    int col  = nt * 32 + (lane & 31);
    int kb   = ks * 16 + (lane >> 5) * 8;
    #pragma unroll
    for (int j = 0; j < 8; ++j)
        dst[(size_t)fid * 8 + j] = (f16_t)src[(kb + j) * 256 + col];
}

// ------------------------------------------------------------------
// Fused prep: weight packs + U/V precompute + innode x-tail.
// blocks [0,32): W2p(32x32)  [32,68): W1op  [68,100): W2op
// [100,1124): Vp + Up + innode tail
// ------------------------------------------------------------------
__global__ void prep_all(const float* __restrict__ x,
                         const float* __restrict__ W_msg1,
                         const float* __restrict__ b_msg1,
                         const float* __restrict__ W_msg2,
                         const float* __restrict__ W_out1,
                         const float* __restrict__ W_out2,
                         f16_t* __restrict__ W2p, f16_t* __restrict__ W1op,
                         f16_t* __restrict__ W2op, f16_t* __restrict__ Vp,
                         f16_t* __restrict__ Up, f16_t* __restrict__ innode)
{
    int bid = blockIdx.x, tid = threadIdx.x;
    if (bid < 32) {
        pack_frag32(W_msg2, W2p, bid * 256 + tid);
    } else if (bid < 68) {
        pack_frag16(W_out1, W1op, (bid - 32) * 256 + tid, 9, 1);
    } else if (bid < 100) {
        pack_frag16(W_out2, W2op, (bid - 68) * 256 + tid, 8, 0);
    } else {
        int gid  = (bid - 100) * 256 + tid;   // 262144
        int rown = gid >> 5;                   // b*64+n
        int hb   = gid & 31;
        int h0   = hb * 8;
        float4 xv = ((const float4*)x)[rown];
        f16x8 ov, ou;
        #pragma unroll
        for (int u = 0; u < 8; ++u) {
            int h = h0 + u;
            float sv = xv.x * W_msg1[4 * HH + h] + xv.y * W_msg1[5 * HH + h]
                     + xv.z * W_msg1[6 * HH + h] + xv.w * W_msg1[7 * HH + h];
            float su = b_msg1[h]
                     + xv.x * W_msg1[0 * HH + h] + xv.y * W_msg1[1 * HH + h]
                     + xv.z * W_msg1[2 * HH + h] + xv.w * W_msg1[3 * HH + h];
            ov[u] = (f16_t)sv;
            ou[u] = (f16_t)su;
        }
        *(f16x8*)(Vp + (size_t)rown * HH + h0) = ov;
        *(f16x8*)(Up + (size_t)rown * HH + h0) = ou;
        // innode x-tail: cols 256..287
        float xt = (hb < 4) ? ((const float*)&xv)[hb] : 0.f;
        innode[(size_t)rown * 288 + 256 + hb] = (f16_t)xt;
    }
}

// ------------------------------------------------------------------
// Edge MLP + aggregation — persistent producer/consumer pipeline.
// 256 blocks (1/CU), 512 threads = 8 waves. Waves 0-3 PRODUCE h1 for
// tile s into buf[s&1] (VALU+LDS-write); waves 4-7 CONSUME tile s-1
// from buf[(s-1)&1] (MFMA+LDS-read). One s_barrier per stage. Each
// SIMD holds 1 producer + 1 consumer wave -> MFMA and VALU pipes run
// simultaneously (m114), no intra-wave write/read alias stall (R7's
// failure mode).
// Per block: 16 tiles (= half a batch: pr 16*(blk&1).. of b=blk>>1).
// h1[r] = relu(U[recv] + V[j]), all from precomputed Up/Vp (L2-hot).
// LDS [128 rows][32 chunks], swizzle chunk^(r&31) (0 conflicts, PMC).
// Consumer wave = 4mt x 2nt, mfma_f32_32x32x16_f16, bias in C-init,
// self rows zeroed by producer, agg -= relu(b2) correction.
// ------------------------------------------------------------------
__global__ __launch_bounds__(512, 2) void edge_kernel(
    const f16_t* __restrict__ Vp,     // [128][64][256]
    const f16_t* __restrict__ Up,     // [128][64][256]
    const f16_t* __restrict__ W2p,    // packed 32x32
    const float* __restrict__ b2,     // [256]
    f16_t* __restrict__ innode)       // [8192][288]
{
    __shared__ __align__(16) char h1[2][128 * 512];   // 128 KiB double buffer

    const int tid  = threadIdx.x;
    const int lane = tid & 63;
    const int w    = tid >> 6;          // 0..7
    const bool producer = (w < 4);
    const int tile0 = blockIdx.x * 16;

    // consumer decomposition (waves 4..7)
    const int ln = lane & 31;
    const int kh = lane >> 5;
    const int wn = w & 3;               // col strip: cols wn*64..+63
    float b2v[2];
    #pragma unroll
    for (int nt = 0; nt < 2; ++nt) b2v[nt] = b2[(wn * 2 + nt) * 32 + ln];

    // producer decomposition (waves 0..3): thread = (rg 0..15) x (hb 0..15)
    const int hb = tid & 15;
    const int rg = tid >> 4;            // valid for tid<256
    const int j0 = (rg & 7) * 8;
    const f16x8 fz = {};

    for (int s = 0; s <= 16; ++s) {
        if (producer && s < 16) {
            const int t  = tile0 + s;
            const int b  = t >> 5;
            const int pr = t & 31;
            const int i0 = pr * 2, i1 = i0 + 1;
            const int recv = (rg < 8) ? i0 : i1;
            char* wb = h1[s & 1];
            const f16x8* vrow = (const f16x8*)(Vp + (size_t)(b * NN + j0) * HH);
            const f16x8* urow = (const f16x8*)(Up + (size_t)(b * NN + recv) * HH);
            #pragma unroll
            for (int half = 0; half < 2; ++half) {
                const int cb = half * 16 + hb;           // logical chunk
                f16x8 u8 = urow[half * 16 + hb];
                #pragma unroll
                for (int k = 0; k < 8; ++k) {
                    int r = rg * 8 + k;                  // sender j = r&63 = j0+k
                    f16x8 v8 = vrow[k * 32 + half * 16 + hb];
                    f16x8 hv = __builtin_elementwise_max(u8 + v8, fz);
                    *(f16x8*)(wb + r * 512 + (((cb ^ (r & 31)) & 31) << 4)) = hv;
                }
                if ((rg & 7) == (recv >> 3)) {           // self-edge row -> 0
                    int r = rg * 8 + (recv & 7);
                    *(f16x8*)(wb + r * 512 + (((cb ^ (r & 31)) & 31) << 4)) = fz;
                }
            }
        }
        if (!producer && s > 0) {
            const int t  = tile0 + s - 1;
            const int b  = t >> 5;
            const int pr = t & 31;
            const int i0 = pr * 2, i1 = i0 + 1;
            const char* rb = h1[(s - 1) & 1];

            f32x16 acc[4][2];
            #pragma unroll
            for (int mt = 0; mt < 4; ++mt)
                #pragma unroll
                for (int nt = 0; nt < 2; ++nt)
                    #pragma unroll
                    for (int e = 0; e < 16; ++e) acc[mt][nt][e] = b2v[nt];

            f16x8 bbn0 = *(const f16x8*)(W2p + (size_t)((wn * 2 + 0) * 64 + lane) * 8);
            f16x8 bbn1 = *(const f16x8*)(W2p + (size_t)((wn * 2 + 1) * 64 + lane) * 8);
            #pragma unroll
            for (int ks = 0; ks < 16; ++ks) {
                f16x8 bb0 = bbn0, bb1 = bbn1;
                if (ks < 15) {
                    bbn0 = *(const f16x8*)(W2p + (size_t)(((ks + 1) * 8 + wn * 2 + 0) * 64 + lane) * 8);
                    bbn1 = *(const f16x8*)(W2p + (size_t)(((ks + 1) * 8 + wn * 2 + 1) * 64 + lane) * 8);
                }
                #pragma unroll
                for (int mt = 0; mt < 4; ++mt) {
                    int row = mt * 32 + ln;
                    int c16 = (ks * 2 + kh) ^ (row & 31);
                    f16x8 a = *(const f16x8*)(rb + row * 512 + (c16 << 4));
                    acc[mt][0] = __builtin_amdgcn_mfma_f32_32x32x16_f16(a, bb0, acc[mt][0], 0, 0, 0);
                    acc[mt][1] = __builtin_amdgcn_mfma_f32_32x32x16_f16(a, bb1, acc[mt][1], 0, 0, 0);
                }
            }

            // relu + row-sum; rows 0..63 -> i0 (mt 0,1), 64..127 -> i1 (mt 2,3)
            float s0[2] = {0.f, 0.f}, s1[2] = {0.f, 0.f};
            #pragma unroll
            for (int mt = 0; mt < 4; ++mt)
                #pragma unroll
                for (int nt = 0; nt < 2; ++nt) {
                    float tacc = 0.f;
                    #pragma unroll
                    for (int e = 0; e < 16; ++e) tacc += fmaxf(acc[mt][nt][e], 0.f);
                    if (mt < 2) s0[nt] += tacc; else s1[nt] += tacc;
                }
            #pragma unroll
            for (int nt = 0; nt < 2; ++nt) {
                s0[nt] += __shfl_xor(s0[nt], 32);
                s1[nt] += __shfl_xor(s1[nt], 32);
            }
            if (lane < 32) {
                #pragma unroll
                for (int nt = 0; nt < 2; ++nt) {
                    float sub = fmaxf(b2v[nt], 0.f);
                    int col = (wn * 2 + nt) * 32 + ln;
                    innode[(size_t)(b * NN + i0) * 288 + col] = (f16_t)(s0[nt] - sub);
                    innode[(size_t)(b * NN + i1) * 288 + col] = (f16_t)(s1[nt] - sub);
                }
            }
        }
        __syncthreads();
    }
}

// ------------------------------------------------------------------
// Node MLP: [8192,288] -> relu 256 -> relu 256 -> 4.
// 512 blocks x 16 rows x 256 threads (4 waves; wave = 1mt x 4nt).
// ------------------------------------------------------------------
__global__ __launch_bounds__(256, 4) void node_kernel(
    const f16_t* __restrict__ innode,  // [8192][288]
    const f16_t* __restrict__ W1op,
    const float* __restrict__ bo1,
    const f16_t* __restrict__ W2op,
    const float* __restrict__ bo2,
    const float* __restrict__ W3,      // [256][4] fp32
    const float* __restrict__ bo3,     // [4]
    float* __restrict__ out)           // [8192][4]
{
    __shared__ __align__(16) char bufA[16 * 640];
    __shared__ __align__(16) char bufB[16 * 512];
    __shared__ __align__(16) char bufC[16 * 528];

    const int tid  = threadIdx.x;
    const int lane = tid & 63;
    const int w    = tid >> 6;          // 0..3 = nt quad
    const int m0   = blockIdx.x * 16;
    const int lm   = lane & 15, lk = lane >> 4;

    for (int idx = tid; idx < 16 * 36; idx += 256) {
        int r = idx / 36, c = idx - r * 36;
        f16x8 v = *(const f16x8*)(innode + (size_t)(m0 + r) * 288 + c * 8);
        *(f16x8*)(bufA + ((r * 640 + c * 16) ^ ((r & 7) << 4))) = v;
    }
    __syncthreads();

    // ---- layer 1: K=288 (9 k-steps), bias in C-init ----
    f32x4 acc1[4];
    #pragma unroll
    for (int nt = 0; nt < 4; ++nt) {
        float bias = bo1[(w * 4 + nt) * 16 + lm];
        acc1[nt] = (f32x4){bias, bias, bias, bias};
    }
    #pragma unroll
    for (int ks = 0; ks < 9; ++ks) {
        f16x8 a = *(const f16x8*)(bufA + ((lm * 640 + ks * 64 + lk * 16) ^ ((lm & 7) << 4)));
        #pragma unroll
        for (int nt = 0; nt < 4; ++nt) {
            f16x8 bb = *(const f16x8*)(W1op + (size_t)((ks * 16 + w * 4 + nt) * 64 + lane) * 8);
            acc1[nt] = __builtin_amdgcn_mfma_f32_16x16x32_f16(a, bb, acc1[nt], 0, 0, 0);
        }
    }
    #pragma unroll
    for (int nt = 0; nt < 4; ++nt) {
        int col = (w * 4 + nt) * 16 + lm;
        #pragma unroll
        for (int j = 0; j < 4; ++j) {
            int row = lk * 4 + j;
            float v = fmaxf(acc1[nt][j], 0.f);
            *(f16_t*)(bufB + ((row * 512 + col * 2) ^ ((row & 7) << 4))) = (f16_t)v;
        }
    }
    __syncthreads();

    // ---- layer 2: K=256 (8 k-steps) ----
    f32x4 acc2[4];
    #pragma unroll
    for (int nt = 0; nt < 4; ++nt) {
        float bias = bo2[(w * 4 + nt) * 16 + lm];
        acc2[nt] = (f32x4){bias, bias, bias, bias};
    }
    #pragma unroll
    for (int ks = 0; ks < 8; ++ks) {
        f16x8 a = *(const f16x8*)(bufB + ((lm * 512 + ks * 64 + lk * 16) ^ ((lm & 7) << 4)));
        #pragma unroll
        for (int nt = 0; nt < 4; ++nt) {
            f16x8 bb = *(const f16x8*)(W2op + (size_t)((ks * 16 + w * 4 + nt) * 64 + lane) * 8);
            acc2[nt] = __builtin_amdgcn_mfma_f32_16x16x32_f16(a, bb, acc2[nt], 0, 0, 0);
        }
    }
    f16_t* c16 = (f16_t*)bufC;
    #pragma unroll
    for (int nt = 0; nt < 4; ++nt) {
        int col = (w * 4 + nt) * 16 + lm;
        #pragma unroll
        for (int j = 0; j < 4; ++j) {
            int row = lk * 4 + j;
            float v = fmaxf(acc2[nt][j], 0.f);
            c16[row * 264 + col] = (f16_t)v;
        }
    }
    __syncthreads();

    // ---- layer 3: [16,256] @ [256,4]; all 256 threads, 4-way k-split ----
    {
        int m = tid >> 4;          // 0..15
        int o = (tid >> 2) & 3;    // 0..3
        int q = tid & 3;           // k quarter
        const f16_t* crow = c16 + m * 264 + q * 64;
        float s = 0.f;
        int rot = (lane & 15) * 4; // rotate k to spread LDS banks
        #pragma unroll 8
        for (int k = 0; k < 64; ++k) {
            int kk = (k + rot) & 63;
            s += (float)crow[kk] * W3[(q * 64 + kk) * 4 + o];
        }
        s += __shfl_xor(s, 1);
        s += __shfl_xor(s, 2);
        if (q == 0) out[(size_t)(m0 + m) * 4 + o] = s + bo3[o];
    }
}

// ------------------------------------------------------------------
extern "C" void kernel_launch(void* const* d_in, const int* in_sizes, int n_in,
                              void* d_out, int out_size, void* d_ws, size_t ws_size,
                              hipStream_t stream)
{
    (void)in_sizes; (void)n_in; (void)out_size; (void)ws_size;
    const float* x      = (const float*)d_in[0];
    const float* W_msg1 = (const float*)d_in[4];
    const float* b_msg1 = (const float*)d_in[5];
    const float* W_msg2 = (const float*)d_in[6];
    const float* b_msg2 = (const float*)d_in[7];
    const float* W_out1 = (const float*)d_in[8];
    const float* b_out1 = (const float*)d_in[9];
    const float* W_out2 = (const float*)d_in[10];
    const float* b_out2 = (const float*)d_in[11];
    const float* W_out3 = (const float*)d_in[12];
    const float* b_out3 = (const float*)d_in[13];
    float* out = (float*)d_out;

    char* ws = (char*)d_ws;
    f16_t* W2p    = (f16_t*)(ws + 0);
    f16_t* W1op   = (f16_t*)(ws + 131072);
    f16_t* W2op   = (f16_t*)(ws + 278528);
    f16_t* innode = (f16_t*)(ws + 409600);
    f16_t* Vp     = (f16_t*)(ws + 5128192);
    f16_t* Up     = (f16_t*)(ws + 9322496);

    prep_all<<<1124, 256, 0, stream>>>(x, W_msg1, b_msg1, W_msg2, W_out1, W_out2,
                                       W2p, W1op, W2op, Vp, Up, innode);
    edge_kernel<<<256, 512, 0, stream>>>(Vp, Up, W2p, b_msg2, innode);
    node_kernel<<<512, 256, 0, stream>>>(innode, W1op, b_out1, W2op, b_out2,
                                         W_out3, b_out3, out);
}

// Round 9
// 119.394 us; speedup vs baseline: 1.2939x; 1.2939x over previous
//
#include <hip/hip_runtime.h>
#include <cstddef>

typedef _Float16 f16_t;
typedef _Float16 f16x8 __attribute__((ext_vector_type(8)));
typedef float    f32x4  __attribute__((ext_vector_type(4)));
typedef float    f32x16 __attribute__((ext_vector_type(16)));

static constexpr int NN = 64;    // nodes
static constexpr int FF = 4;     // features
static constexpr int HH = 256;   // hidden

// ---- workspace layout (bytes) ----
// W2p    @ 0        : 131072   (W_msg2 packed 32x32x16 B-frags, f16)
// W1op   @ 131072   : 147456   (W_out1 padded/remapped 16x16x32, f16)
// W2op   @ 278528   : 131072   (W_out2 packed 16x16x32, f16)
// innode @ 409600   : 4718592  ([agg(256) | x(4) | pad(28)] f16, 8192 rows)
// Vp     @ 5128192  : 4194304  (V = x @ W1[4:8], f16 [128][64][256])
// Up     @ 9322496  : 4194304  (U = x @ W1[0:4] + b1, f16 [128][64][256])

// ------------------------------------------------------------------
// 16x16x32 B-frag pack: lane holds B[k=ks*32+(lane>>4)*8+j][col=nt*16+(lane&15)]
// ------------------------------------------------------------------
__device__ inline void pack_frag16(const float* __restrict__ src, f16_t* __restrict__ dst,
                                   int fid, int ksteps, int mode)
{
    if (fid >= ksteps * 1024) return;
    int lane = fid & 63;
    int nt   = (fid >> 6) & 15;
    int ks   = fid >> 10;
    int col  = nt * 16 + (lane & 15);
    int kb   = ks * 32 + (lane >> 4) * 8;
    #pragma unroll
    for (int j = 0; j < 8; ++j) {
        int k = kb + j;
        float v;
        if (mode == 0) {
            v = src[k * 256 + col];
        } else {
            if (k < 256)      v = src[(4 + k) * 256 + col];
            else if (k < 260) v = src[(k - 256) * 256 + col];
            else              v = 0.f;
        }
        dst[(size_t)fid * 8 + j] = (f16_t)v;
    }
}

// ------------------------------------------------------------------
// 32x32x16 B-frag pack: lane holds B[k=ks*16+(lane>>5)*8+j][col=nt*32+(lane&31)]
// ------------------------------------------------------------------
__device__ inline void pack_frag32(const float* __restrict__ src, f16_t* __restrict__ dst,
                                   int fid)
{
    int lane = fid & 63;
    int nt   = (fid >> 6) & 7;
    int ks   = fid >> 9;
    int col  = nt * 32 + (lane & 31);
    int kb   = ks * 16 + (lane >> 5) * 8;
    #pragma unroll
    for (int j = 0; j < 8; ++j)
        dst[(size_t)fid * 8 + j] = (f16_t)src[(kb + j) * 256 + col];
}

// ------------------------------------------------------------------
// Fused prep: weight packs + U/V precompute + innode x-tail.
// blocks [0,32): W2p(32x32)  [32,68): W1op  [68,100): W2op
// [100,1124): Vp + Up + innode tail
// ------------------------------------------------------------------
__global__ void prep_all(const float* __restrict__ x,
                         const float* __restrict__ W_msg1,
                         const float* __restrict__ b_msg1,
                         const float* __restrict__ W_msg2,
                         const float* __restrict__ W_out1,
                         const float* __restrict__ W_out2,
                         f16_t* __restrict__ W2p, f16_t* __restrict__ W1op,
                         f16_t* __restrict__ W2op, f16_t* __restrict__ Vp,
                         f16_t* __restrict__ Up, f16_t* __restrict__ innode)
{
    int bid = blockIdx.x, tid = threadIdx.x;
    if (bid < 32) {
        pack_frag32(W_msg2, W2p, bid * 256 + tid);
    } else if (bid < 68) {
        pack_frag16(W_out1, W1op, (bid - 32) * 256 + tid, 9, 1);
    } else if (bid < 100) {
        pack_frag16(W_out2, W2op, (bid - 68) * 256 + tid, 8, 0);
    } else {
        int gid  = (bid - 100) * 256 + tid;   // 262144
        int rown = gid >> 5;                   // b*64+n
        int hb   = gid & 31;
        int h0   = hb * 8;
        float4 xv = ((const float4*)x)[rown];
        f16x8 ov, ou;
        #pragma unroll
        for (int u = 0; u < 8; ++u) {
            int h = h0 + u;
            float sv = xv.x * W_msg1[4 * HH + h] + xv.y * W_msg1[5 * HH + h]
                     + xv.z * W_msg1[6 * HH + h] + xv.w * W_msg1[7 * HH + h];
            float su = b_msg1[h]
                     + xv.x * W_msg1[0 * HH + h] + xv.y * W_msg1[1 * HH + h]
                     + xv.z * W_msg1[2 * HH + h] + xv.w * W_msg1[3 * HH + h];
            ov[u] = (f16_t)sv;
            ou[u] = (f16_t)su;
        }
        *(f16x8*)(Vp + (size_t)rown * HH + h0) = ov;
        *(f16x8*)(Up + (size_t)rown * HH + h0) = ou;
        // innode x-tail: cols 256..287
        float xt = (hb < 4) ? ((const float*)&xv)[hb] : 0.f;
        innode[(size_t)rown * 288 + 256 + hb] = (f16_t)xt;
    }
}

// ------------------------------------------------------------------
// Edge MLP + aggregation — R6 skeleton + T14 half-K pipeline.
// One block = (batch b, receivers i0,i1); 256 threads = 4 waves.
// P0: build h1 logical chunks 0..15 (k 0..127), relu(U+V) from
//     precomputed Up/Vp. barrier.
// P1: ISSUE half-1 global loads (9x16B/thread) -> run MFMA ks 0..7
//     (reads logical half-0 only; per-row XOR swizzle keeps halves
//     byte-disjoint per row -> no race) -> pk-compute + ds_write
//     half-1 AFTER the cluster (loads' latency hidden under MFMA).
//     barrier.
// P2: MFMA ks 8..15 + relu-rowsum epilogue.
// Wave = 4mt x 2nt, mfma_f32_32x32x16_f16, bias in C-init, self rows
// zeroed, agg -= relu(b2). Swizzle byte-identical to R6 (0 conflicts).
// ------------------------------------------------------------------
__global__ __launch_bounds__(256, 2) void edge_kernel(
    const f16_t* __restrict__ Vp,     // [128][64][256]
    const f16_t* __restrict__ Up,     // [128][64][256]
    const f16_t* __restrict__ W2p,    // packed 32x32
    const float* __restrict__ b2,     // [256]
    f16_t* __restrict__ innode)       // [8192][288]
{
    __shared__ __align__(16) char h1[128 * 512];   // 64 KiB f16, swizzled

    const int tid  = threadIdx.x;
    const int lane = tid & 63;
    const int w    = tid >> 6;        // 0..3 = wn (col strip)
    const int b    = blockIdx.x >> 5;
    const int pr   = blockIdx.x & 31;
    const int i0   = pr * 2, i1 = i0 + 1;

    // producer mapping: thread = (rg 0..15: 8 rows) x (hb 0..15: chunk col)
    const int hb = tid & 15;
    const int rg = tid >> 4;
    const int recv = (rg < 8) ? i0 : i1;
    const int j0 = (rg & 7) * 8;
    const f16x8 fz = {};
    const f16x8* vrow = (const f16x8*)(Vp + (size_t)(b * NN + j0) * HH);
    const f16x8* urow = (const f16x8*)(Up + (size_t)(b * NN + recv) * HH);

    // consumer mapping
    const int ln = lane & 31;
    const int kh = lane >> 5;
    const int wn = w;
    float b2v[2];
    #pragma unroll
    for (int nt = 0; nt < 2; ++nt) b2v[nt] = b2[(wn * 2 + nt) * 32 + ln];

    // B prefetch for ks=0 (independent of barriers)
    f16x8 bbn0 = *(const f16x8*)(W2p + (size_t)((wn * 2 + 0) * 64 + lane) * 8);
    f16x8 bbn1 = *(const f16x8*)(W2p + (size_t)((wn * 2 + 1) * 64 + lane) * 8);

    // ---- P0: h1 logical chunks 0..15 ----
    {
        f16x8 u8 = urow[hb];
        #pragma unroll
        for (int k = 0; k < 8; ++k) {
            int r = rg * 8 + k;                 // sender j = j0+k = r&63
            f16x8 v8 = vrow[k * 32 + hb];
            f16x8 hv = __builtin_elementwise_max(u8 + v8, fz);
            *(f16x8*)(h1 + r * 512 + (((hb ^ (r & 31)) & 31) << 4)) = hv;
        }
        if ((rg & 7) == (recv >> 3)) {          // self-edge row -> 0
            int r = rg * 8 + (recv & 7);
            *(f16x8*)(h1 + r * 512 + (((hb ^ (r & 31)) & 31) << 4)) = fz;
        }
    }
    __syncthreads();

    // ---- stage half-1: issue loads NOW (complete under P1's MFMAs) ----
    f16x8 su  = urow[16 + hb];
    f16x8 sv0 = vrow[0 * 32 + 16 + hb];
    f16x8 sv1 = vrow[1 * 32 + 16 + hb];
    f16x8 sv2 = vrow[2 * 32 + 16 + hb];
    f16x8 sv3 = vrow[3 * 32 + 16 + hb];
    f16x8 sv4 = vrow[4 * 32 + 16 + hb];
    f16x8 sv5 = vrow[5 * 32 + 16 + hb];
    f16x8 sv6 = vrow[6 * 32 + 16 + hb];
    f16x8 sv7 = vrow[7 * 32 + 16 + hb];

    // ---- acc init (bias in C) ----
    f32x16 acc[4][2];
    #pragma unroll
    for (int mt = 0; mt < 4; ++mt)
        #pragma unroll
        for (int nt = 0; nt < 2; ++nt)
            #pragma unroll
            for (int e = 0; e < 16; ++e) acc[mt][nt][e] = b2v[nt];

    // ---- P1: GEMM ks 0..7 (reads logical half-0) ----
    __builtin_amdgcn_s_setprio(1);
    #pragma unroll
    for (int ks = 0; ks < 8; ++ks) {
        f16x8 bb0 = bbn0, bb1 = bbn1;
        bbn0 = *(const f16x8*)(W2p + (size_t)(((ks + 1) * 8 + wn * 2 + 0) * 64 + lane) * 8);
        bbn1 = *(const f16x8*)(W2p + (size_t)(((ks + 1) * 8 + wn * 2 + 1) * 64 + lane) * 8);
        #pragma unroll
        for (int mt = 0; mt < 4; ++mt) {
            int row = mt * 32 + ln;
            int c16 = (ks * 2 + kh) ^ (row & 31);
            f16x8 a = *(const f16x8*)(h1 + row * 512 + (c16 << 4));
            acc[mt][0] = __builtin_amdgcn_mfma_f32_32x32x16_f16(a, bb0, acc[mt][0], 0, 0, 0);
            acc[mt][1] = __builtin_amdgcn_mfma_f32_32x32x16_f16(a, bb1, acc[mt][1], 0, 0, 0);
        }
    }
    __builtin_amdgcn_s_setprio(0);

    // ---- stage half-1 finish: compute + store (write-late) ----
    {
        f16x8 hv;
        #define ST(kk, svk)                                                          \
            {                                                                        \
                int r = rg * 8 + kk;                                                 \
                hv = __builtin_elementwise_max(su + svk, fz);                        \
                *(f16x8*)(h1 + r * 512 + ((((16 + hb) ^ (r & 31)) & 31) << 4)) = hv; \
            }
        ST(0, sv0) ST(1, sv1) ST(2, sv2) ST(3, sv3)
        ST(4, sv4) ST(5, sv5) ST(6, sv6) ST(7, sv7)
        #undef ST
        if ((rg & 7) == (recv >> 3)) {
            int r = rg * 8 + (recv & 7);
            *(f16x8*)(h1 + r * 512 + ((((16 + hb) ^ (r & 31)) & 31) << 4)) = fz;
        }
    }
    __syncthreads();

    // ---- P2: GEMM ks 8..15 (bbn holds ks=8 frags from P1's prefetch) ----
    __builtin_amdgcn_s_setprio(1);
    #pragma unroll
    for (int ks = 8; ks < 16; ++ks) {
        f16x8 bb0 = bbn0, bb1 = bbn1;
        if (ks < 15) {
            bbn0 = *(const f16x8*)(W2p + (size_t)(((ks + 1) * 8 + wn * 2 + 0) * 64 + lane) * 8);
            bbn1 = *(const f16x8*)(W2p + (size_t)(((ks + 1) * 8 + wn * 2 + 1) * 64 + lane) * 8);
        }
        #pragma unroll
        for (int mt = 0; mt < 4; ++mt) {
            int row = mt * 32 + ln;
            int c16 = (ks * 2 + kh) ^ (row & 31);
            f16x8 a = *(const f16x8*)(h1 + row * 512 + (c16 << 4));
            acc[mt][0] = __builtin_amdgcn_mfma_f32_32x32x16_f16(a, bb0, acc[mt][0], 0, 0, 0);
            acc[mt][1] = __builtin_amdgcn_mfma_f32_32x32x16_f16(a, bb1, acc[mt][1], 0, 0, 0);
        }
    }
    __builtin_amdgcn_s_setprio(0);

    // ---- relu + row-sum; rows 0..63 -> i0 (mt 0,1), 64..127 -> i1 (mt 2,3) ----
    // C layout 32x32: col = lane&31, row = (e&3) + 8*(e>>2) + 4*(lane>>5)
    float s0[2] = {0.f, 0.f}, s1[2] = {0.f, 0.f};
    #pragma unroll
    for (int mt = 0; mt < 4; ++mt)
        #pragma unroll
        for (int nt = 0; nt < 2; ++nt) {
            float t = 0.f;
            #pragma unroll
            for (int e = 0; e < 16; ++e) t += fmaxf(acc[mt][nt][e], 0.f);
            if (mt < 2) s0[nt] += t; else s1[nt] += t;
        }
    #pragma unroll
    for (int nt = 0; nt < 2; ++nt) {
        s0[nt] += __shfl_xor(s0[nt], 32);
        s1[nt] += __shfl_xor(s1[nt], 32);
    }
    if (lane < 32) {
        #pragma unroll
        for (int nt = 0; nt < 2; ++nt) {
            float sub = fmaxf(b2v[nt], 0.f);
            int col = (wn * 2 + nt) * 32 + ln;
            innode[(size_t)(b * NN + i0) * 288 + col] = (f16_t)(s0[nt] - sub);
            innode[(size_t)(b * NN + i1) * 288 + col] = (f16_t)(s1[nt] - sub);
        }
    }
}

// ------------------------------------------------------------------
// Node MLP: [8192,288] -> relu 256 -> relu 256 -> 4.
// 512 blocks x 16 rows x 256 threads (4 waves; wave = 1mt x 4nt).
// ------------------------------------------------------------------
__global__ __launch_bounds__(256, 4) void node_kernel(
    const f16_t* __restrict__ innode,  // [8192][288]
    const f16_t* __restrict__ W1op,
    const float* __restrict__ bo1,
    const f16_t* __restrict__ W2op,
    const float* __restrict__ bo2,
    const float* __restrict__ W3,      // [256][4] fp32
    const float* __restrict__ bo3,     // [4]
    float* __restrict__ out)           // [8192][4]
{
    __shared__ __align__(16) char bufA[16 * 640];
    __shared__ __align__(16) char bufB[16 * 512];
    __shared__ __align__(16) char bufC[16 * 528];

    const int tid  = threadIdx.x;
    const int lane = tid & 63;
    const int w    = tid >> 6;          // 0..3 = nt quad
    const int m0   = blockIdx.x * 16;
    const int lm   = lane & 15, lk = lane >> 4;

    for (int idx = tid; idx < 16 * 36; idx += 256) {
        int r = idx / 36, c = idx - r * 36;
        f16x8 v = *(const f16x8*)(innode + (size_t)(m0 + r) * 288 + c * 8);
        *(f16x8*)(bufA + ((r * 640 + c * 16) ^ ((r & 7) << 4))) = v;
    }
    __syncthreads();

    // ---- layer 1: K=288 (9 k-steps), bias in C-init ----
    f32x4 acc1[4];
    #pragma unroll
    for (int nt = 0; nt < 4; ++nt) {
        float bias = bo1[(w * 4 + nt) * 16 + lm];
        acc1[nt] = (f32x4){bias, bias, bias, bias};
    }
    #pragma unroll
    for (int ks = 0; ks < 9; ++ks) {
        f16x8 a = *(const f16x8*)(bufA + ((lm * 640 + ks * 64 + lk * 16) ^ ((lm & 7) << 4)));
        #pragma unroll
        for (int nt = 0; nt < 4; ++nt) {
            f16x8 bb = *(const f16x8*)(W1op + (size_t)((ks * 16 + w * 4 + nt) * 64 + lane) * 8);
            acc1[nt] = __builtin_amdgcn_mfma_f32_16x16x32_f16(a, bb, acc1[nt], 0, 0, 0);
        }
    }
    #pragma unroll
    for (int nt = 0; nt < 4; ++nt) {
        int col = (w * 4 + nt) * 16 + lm;
        #pragma unroll
        for (int j = 0; j < 4; ++j) {
            int row = lk * 4 + j;
            float v = fmaxf(acc1[nt][j], 0.f);
            *(f16_t*)(bufB + ((row * 512 + col * 2) ^ ((row & 7) << 4))) = (f16_t)v;
        }
    }
    __syncthreads();

    // ---- layer 2: K=256 (8 k-steps) ----
    f32x4 acc2[4];
    #pragma unroll
    for (int nt = 0; nt < 4; ++nt) {
        float bias = bo2[(w * 4 + nt) * 16 + lm];
        acc2[nt] = (f32x4){bias, bias, bias, bias};
    }
    #pragma unroll
    for (int ks = 0; ks < 8; ++ks) {
        f16x8 a = *(const f16x8*)(bufB + ((lm * 512 + ks * 64 + lk * 16) ^ ((lm & 7) << 4)));
        #pragma unroll
        for (int nt = 0; nt < 4; ++nt) {
            f16x8 bb = *(const f16x8*)(W2op + (size_t)((ks * 16 + w * 4 + nt) * 64 + lane) * 8);
            acc2[nt] = __builtin_amdgcn_mfma_f32_16x16x32_f16(a, bb, acc2[nt], 0, 0, 0);
        }
    }
    f16_t* c16 = (f16_t*)bufC;
    #pragma unroll
    for (int nt = 0; nt < 4; ++nt) {
        int col = (w * 4 + nt) * 16 + lm;
        #pragma unroll
        for (int j = 0; j < 4; ++j) {
            int row = lk * 4 + j;
            float v = fmaxf(acc2[nt][j], 0.f);
            c16[row * 264 + col] = (f16_t)v;
        }
    }
    __syncthreads();

    // ---- layer 3: [16,256] @ [256,4]; all 256 threads, 4-way k-split ----
    {
        int m = tid >> 4;          // 0..15
        int o = (tid >> 2) & 3;    // 0..3
        int q = tid & 3;           // k quarter
        const f16_t* crow = c16 + m * 264 + q * 64;
        float s = 0.f;
        int rot = (lane & 15) * 4; // rotate k to spread LDS banks
        #pragma unroll 8
        for (int k = 0; k < 64; ++k) {
            int kk = (k + rot) & 63;
            s += (float)crow[kk] * W3[(q * 64 + kk) * 4 + o];
        }
        s += __shfl_xor(s, 1);
        s += __shfl_xor(s, 2);
        if (q == 0) out[(size_t)(m0 + m) * 4 + o] = s + bo3[o];
    }
}

// ------------------------------------------------------------------
extern "C" void kernel_launch(void* const* d_in, const int* in_sizes, int n_in,
                              void* d_out, int out_size, void* d_ws, size_t ws_size,
                              hipStream_t stream)
{
    (void)in_sizes; (void)n_in; (void)out_size; (void)ws_size;
    const float* x      = (const float*)d_in[0];
    const float* W_msg1 = (const float*)d_in[4];
    const float* b_msg1 = (const float*)d_in[5];
    const float* W_msg2 = (const float*)d_in[6];
    const float* b_msg2 = (const float*)d_in[7];
    const float* W_out1 = (const float*)d_in[8];
    const float* b_out1 = (const float*)d_in[9];
    const float* W_out2 = (const float*)d_in[10];
    const float* b_out2 = (const float*)d_in[11];
    const float* W_out3 = (const float*)d_in[12];
    const float* b_out3 = (const float*)d_in[13];
    float* out = (float*)d_out;

    char* ws = (char*)d_ws;
    f16_t* W2p    = (f16_t*)(ws + 0);
    f16_t* W1op   = (f16_t*)(ws + 131072);
    f16_t* W2op   = (f16_t*)(ws + 278528);
    f16_t* innode = (f16_t*)(ws + 409600);
    f16_t* Vp     = (f16_t*)(ws + 5128192);
    f16_t* Up     = (f16_t*)(ws + 9322496);

    prep_all<<<1124, 256, 0, stream>>>(x, W_msg1, b_msg1, W_msg2, W_out1, W_out2,
                                       W2p, W1op, W2op, Vp, Up, innode);
    edge_kernel<<<4096, 256, 0, stream>>>(Vp, Up, W2p, b_msg2, innode);
    node_kernel<<<512, 256, 0, stream>>>(innode, W1op, b_out1, W2op, b_out2,
                                         W_out3, b_out3, out);
}